// Round 2
// baseline (9369.221 us; speedup 1.0000x reference)
//
#include <hip/hip_runtime.h>
#include <hip/hip_bf16.h>
#include <math.h>

// LSTM: S=512, B=64, I=1024, H=1024
// out[S,B,H] fp32, then h_last[B,H], c_last[B,H]
//
//  1) convert x,W_ih,W_hh -> bf16 in ws
//  2) gates_x[S*B,4H] = x @ W_ih^T  (128x128 MFMA GEMM, bf16 out)
//  3) ONE persistent cooperative kernel runs all 512 steps.
//     Sync design (R5): producers publish h with sc1 (agent) stores into a
//     fresh 128 KiB ring slot per step (ring overlays dead xb); flags
//     polled by wave0 with sc1 loads. Consumers feed the MFMA A-operand
//     DIRECTLY from the ring with plain cached global_load_dwordx4
//     (fragment = 16 contiguous bytes/lane) -- no LDS h staging at all.
//     R1/R4 counters proved h is L2-deduped per XCD either way (FETCH ~=
//     1 MiB/step); what the Hs path cost was ~2500 LDS-pipe cycles + 2
//     barriers + 7.5e7 bank-conflict cycles per dispatch. All deleted.

#define S_LEN 512
#define BATCH 64
#define IDIM 1024
#define HDIM 1024
#define GDIM 4096
#define MAGIC 0x1337BEEFu
#define HSLOT (BATCH * HDIM)   // 65536 ushorts = 128 KiB per ring slot

typedef __bf16 bf16x8 __attribute__((ext_vector_type(8)));
typedef float f32x4 __attribute__((ext_vector_type(4)));

__device__ inline ushort f2b(float f) {
    union { float f; unsigned u; } v; v.f = f;
    unsigned u = v.u;
    unsigned r = (u + 0x7fffu + ((u >> 16) & 1u)) >> 16;
    return (ushort)r;
}
__device__ inline float b2f(ushort u) {
    union { unsigned u; float f; } v; v.u = ((unsigned)u) << 16;
    return v.f;
}
__device__ inline float sigmoidf_(float x) { return 1.f / (1.f + __expf(-x)); }
__device__ inline float tanhf_(float x) {
    return 1.f - 2.f / (__expf(2.f * x) + 1.f);
}

// ---------- conversion kernels ----------
__global__ __launch_bounds__(256) void f2b_kernel(ushort* __restrict__ dst,
                                                  const float* __restrict__ src, int n) {
    int i = (blockIdx.x * 256 + threadIdx.x) * 4;
    if (i < n) {
        float4 v = *(const float4*)(src + i);
        ushort4 o;
        o.x = f2b(v.x); o.y = f2b(v.y); o.z = f2b(v.z); o.w = f2b(v.w);
        *(ushort4*)(dst + i) = o;
    }
}

__global__ __launch_bounds__(256) void bias_kernel(float* __restrict__ bias,
                                                   const float* __restrict__ b_ih,
                                                   const float* __restrict__ b_hh) {
    int i = blockIdx.x * 256 + threadIdx.x;
    if (i < GDIM) bias[i] = b_ih[i] + b_hh[i];
}

// ---------- big GEMM: C[M,N] = A[M,K] @ B[N,K]^T ----------
#define LDSS 72
__global__ __launch_bounds__(256) void gemm_bt_kernel(const ushort* __restrict__ A,
                                                      const ushort* __restrict__ B,
                                                      ushort* __restrict__ C,
                                                      int M, int N, int K) {
    __shared__ __align__(16) ushort As[128 * LDSS];
    __shared__ __align__(16) ushort Bs[128 * LDSS];
    const int tid = threadIdx.x;
    const int lane = tid & 63;
    const int wave = tid >> 6;
    const int l15 = lane & 15;
    const int quad = lane >> 4;
    const int bn = blockIdx.x;
    const int bm = blockIdx.y;
    const int wrow = (wave & 1) * 64;
    const int wcol = (wave >> 1) * 64;

    f32x4 acc[4][4] = {};

    for (int kt = 0; kt < K; kt += 64) {
        #pragma unroll
        for (int i = 0; i < 4; i++) {
            int chunk = tid + i * 256;
            int r = chunk >> 3;
            int c8 = (chunk & 7) * 8;
            *(uint4*)&As[r * LDSS + c8] =
                *(const uint4*)&A[(size_t)(bm * 128 + r) * K + kt + c8];
            *(uint4*)&Bs[r * LDSS + c8] =
                *(const uint4*)&B[(size_t)(bn * 128 + r) * K + kt + c8];
        }
        __syncthreads();
        #pragma unroll
        for (int kc = 0; kc < 2; kc++) {
            const int ko = kc * 32 + quad * 8;
            bf16x8 af[4], bf[4];
            #pragma unroll
            for (int m = 0; m < 4; m++)
                af[m] = *(const bf16x8*)&As[(wrow + m * 16 + l15) * LDSS + ko];
            #pragma unroll
            for (int n = 0; n < 4; n++)
                bf[n] = *(const bf16x8*)&Bs[(wcol + n * 16 + l15) * LDSS + ko];
            #pragma unroll
            for (int m = 0; m < 4; m++)
                #pragma unroll
                for (int n = 0; n < 4; n++)
                    acc[m][n] = __builtin_amdgcn_mfma_f32_16x16x32_bf16(af[m], bf[n], acc[m][n], 0, 0, 0);
        }
        __syncthreads();
    }
    const int col0 = bn * 128 + wcol;
    const int row0 = bm * 128 + wrow;
    #pragma unroll
    for (int m = 0; m < 4; m++) {
        #pragma unroll
        for (int n = 0; n < 4; n++) {
            int col = col0 + n * 16 + l15;
            int rbase = row0 + m * 16 + quad * 4;
            #pragma unroll
            for (int r = 0; r < 4; r++)
                C[(size_t)(rbase + r) * N + col] = f2b(acc[m][n][r]);
        }
    }
}

// ---------- persistent recurrence kernel ----------
// 64 blocks x 512 threads (8 waves). Block b owns h-cols [b*16, b*16+16).
// Wave wv: gate = wv&3, mw = wv>>2 (batches mw*32..+32, 2 m-frags).
// W_hh b-frags for full K=1024 in registers (32 x bf16x8 = 128 regs/wave).
// A-operand (h) loaded DIRECTLY from the ring slot via cached 16B loads:
// frag = h[mw*32 (+16) + l15][ks*32 + quad*8 ..+8], 2-group double buffer.
#define GSB 18          // Gs per-batch stride (floats)

__global__ __launch_bounds__(512) void lstm_persistent(
    const ushort* __restrict__ gx,
    ushort* __restrict__ hring,
    const ushort* __restrict__ Whh,
    const float* __restrict__ bias,
    const float* __restrict__ c0,
    float* __restrict__ out,
    unsigned* __restrict__ flags)
{
    __shared__ float Gs[4 * 64 * GSB];               // 18,432 B (only LDS)

    const int tid = threadIdx.x;
    const int lane = tid & 63;
    const int wv = tid >> 6;
    const int gate = wv & 3;
    const int mw = wv >> 2;
    const int l15 = lane & 15;
    const int quad = lane >> 4;
    const int blk = blockIdx.x;

    // ---- preload W fragments (once): B-frag rows gate*1024+blk*16+l15 ----
    bf16x8 wf[32];
    {
        const ushort* wrow = Whh + ((size_t)(gate * 1024 + blk * 16 + l15)) * 1024 + quad * 8;
        #pragma unroll
        for (int ks = 0; ks < 32; ks++)
            wf[ks] = *(const bf16x8*)(wrow + ks * 32);
    }

    // ---- pointwise per-thread state: elements (pb, pj) and (pb, pj+1) ----
    const int pb = tid >> 3;
    const int pj = (tid * 2) & 15;
    const int pcol = blk * 16 + pj;
    float2 creg = *(const float2*)&c0[(size_t)pb * HDIM + pcol];
    float bsum[4][2];
    #pragma unroll
    for (int g = 0; g < 4; g++) {
        bsum[g][0] = bias[g * 1024 + pcol];
        bsum[g][1] = bias[g * 1024 + pcol + 1];
    }
    const size_t gx_tb = (size_t)pb * GDIM + blk * 16 + pj;

    // per-wave A-frag base offsets (elem units; ring slot added per step)
    const size_t a0_off = (size_t)(mw * 32 + l15) * HDIM + quad * 8;
    const size_t a1_off = a0_off + (size_t)16 * HDIM;

    #pragma unroll 1
    for (int s = 0; s < S_LEN; s++) {
        const ushort* hsrc = hring + (size_t)s * HSLOT;

        // prefetch gx[s] (independent of h) before the flag wait
        ushort2 gxr[4];
        {
            const ushort* gxs = gx + (size_t)s * BATCH * GDIM + gx_tb;
            #pragma unroll
            for (int g = 0; g < 4; g++)
                gxr[g] = *(const ushort2*)(gxs + g * 1024);
        }

        // wait for h_s: wave0 polls all 64 per-block flags in one wave load.
        // RELAXED+AGENT = sc1 load (LLC-coherent), no buffer_inv.
        if (s > 0) {
            if (wv == 0) {
                const unsigned* fl = flags + (size_t)s * 64;
                while (true) {
                    unsigned v = __hip_atomic_load(&fl[lane], __ATOMIC_RELAXED,
                                                   __HIP_MEMORY_SCOPE_AGENT);
                    if (__ballot(v != MAGIC) == 0ull) break;
                    __builtin_amdgcn_s_sleep(2);
                }
            }
            __syncthreads();   // also fences the plain h loads below the poll
        }

        // MFMA over K=1024, A direct from ring (plain cached 16B loads; ring
        // slot is a fresh address -> producers' sc1 stores in LLC are the
        // only version; XCD L2 dedups across the 8 local blocks).
        f32x4 acc0 = {0.f, 0.f, 0.f, 0.f};
        f32x4 acc1 = {0.f, 0.f, 0.f, 0.f};
        {
            const ushort* a0p = hsrc + a0_off;
            const ushort* a1p = hsrc + a1_off;
            bf16x8 ab[2][8];   // 2-group double buffer: 4 ks-slices x 2 rows

            #define LOADG(B, G)                                              \
                do {                                                         \
                    _Pragma("unroll")                                        \
                    for (int j = 0; j < 4; j++) {                            \
                        ab[B][j]     = *(const bf16x8*)(a0p + ((G)*4 + j) * 32); \
                        ab[B][4 + j] = *(const bf16x8*)(a1p + ((G)*4 + j) * 32); \
                    }                                                        \
                } while (0)

            LOADG(0, 0);
            #pragma unroll
            for (int g = 0; g < 8; g++) {
                const int cur = g & 1;
                if (g < 7) LOADG(cur ^ 1, g + 1);
                #pragma unroll
                for (int j = 0; j < 4; j++) {
                    acc0 = __builtin_amdgcn_mfma_f32_16x16x32_bf16(ab[cur][j],     wf[g*4 + j], acc0, 0, 0, 0);
                    acc1 = __builtin_amdgcn_mfma_f32_16x16x32_bf16(ab[cur][4 + j], wf[g*4 + j], acc1, 0, 0, 0);
                }
            }
            #undef LOADG
        }

        // exchange gates through LDS (C layout: col=lane&15, row=quad*4+reg)
        #pragma unroll
        for (int f = 0; f < 2; f++) {
            f32x4 a = f ? acc1 : acc0;
            int b0 = mw * 32 + f * 16 + quad * 4;
            #pragma unroll
            for (int r = 0; r < 4; r++)
                Gs[gate * (64 * GSB) + (b0 + r) * GSB + l15] = a[r];
        }
        __syncthreads();

        // pointwise: 2 elements per thread
        float hv[2], cv[2];
        #pragma unroll
        for (int u = 0; u < 2; u++) {
            float cold = u ? creg.y : creg.x;
            float g0 = Gs[0 * 64 * GSB + pb * GSB + pj + u] + bsum[0][u] + b2f(u ? gxr[0].y : gxr[0].x);
            float g1 = Gs[1 * 64 * GSB + pb * GSB + pj + u] + bsum[1][u] + b2f(u ? gxr[1].y : gxr[1].x);
            float g2 = Gs[2 * 64 * GSB + pb * GSB + pj + u] + bsum[2][u] + b2f(u ? gxr[2].y : gxr[2].x);
            float g3 = Gs[3 * 64 * GSB + pb * GSB + pj + u] + bsum[3][u] + b2f(u ? gxr[3].y : gxr[3].x);
            float ig = sigmoidf_(g0);
            float fg = sigmoidf_(g1);
            float gg = tanhf_(g2);
            float og = sigmoidf_(g3);
            float cn = fg * cold + ig * gg;
            float hn = og * tanhf_(cn);
            cv[u] = cn; hv[u] = hn;
        }
        creg.x = cv[0]; creg.y = cv[1];
        float2 ho; ho.x = hv[0]; ho.y = hv[1];

        // publish h_{s+1} into the NEXT ring slot: sc1 write-through store
        // (4B packed bf16x2). Skipped on the last step (tail comes from regs).
        if (s < S_LEN - 1) {
            ushort* hdst = hring + (size_t)(s + 1) * HSLOT;
            unsigned hword = (unsigned)f2b(hv[0]) | ((unsigned)f2b(hv[1]) << 16);
            __hip_atomic_store((unsigned*)&hdst[(size_t)pb * HDIM + pcol], hword,
                               __ATOMIC_RELAXED, __HIP_MEMORY_SCOPE_AGENT);
        }

        // __syncthreads drains vmcnt(0) per wave: all sc1 h stores acked at
        // the coherence point (LLC) before the flag store issues.
        __syncthreads();
        if (tid == 0 && s < S_LEN - 1) {
            asm volatile("s_waitcnt vmcnt(0)" ::: "memory");
            __hip_atomic_store(&flags[(size_t)(s + 1) * 64 + blk], MAGIC,
                               __ATOMIC_RELAXED, __HIP_MEMORY_SCOPE_AGENT);
        }

        // out store AFTER the flag publish: HBM write ack overlaps the next
        // step's poll instead of sitting on the handoff path.
        *(float2*)&out[(size_t)s * BATCH * HDIM + (size_t)pb * HDIM + pcol] = ho;

        if (s == S_LEN - 1) {
            float* tail = out + (size_t)S_LEN * BATCH * HDIM;
            *(float2*)&tail[(size_t)pb * HDIM + pcol] = ho;
            float2 co; co.x = cv[0]; co.y = cv[1];
            *(float2*)&tail[BATCH * HDIM + (size_t)pb * HDIM + pcol] = co;
        }
    }
}

extern "C" void kernel_launch(void* const* d_in, const int* in_sizes, int n_in,
                              void* d_out, int out_size, void* d_ws, size_t ws_size,
                              hipStream_t stream) {
    const float* x    = (const float*)d_in[0];
    const float* h0   = (const float*)d_in[1];
    const float* c0   = (const float*)d_in[2];
    const float* W_ih = (const float*)d_in[3];
    const float* b_ih = (const float*)d_in[4];
    const float* W_hh = (const float*)d_in[5];
    const float* b_hh = (const float*)d_in[6];
    float* out = (float*)d_out;

    const size_t n_x  = (size_t)S_LEN * BATCH * IDIM;
    const size_t n_w  = (size_t)GDIM * IDIM;
    // xb (64 MiB) doubles as the h ring: 512 slots x 128 KiB, reused only
    // after the GEMM has consumed x.
    const size_t o_xb    = 0;
    const size_t o_gx    = o_xb + n_x * 2;
    const size_t o_wih   = o_gx + (size_t)S_LEN * BATCH * GDIM * 2;
    const size_t o_whh   = o_wih + n_w * 2;
    const size_t o_bias  = o_whh + n_w * 2;
    const size_t o_flags = o_bias + GDIM * 4;
    const size_t flags_bytes = (size_t)(S_LEN + 1) * 64 * 4;
    const size_t total  = o_flags + flags_bytes;
    if (ws_size < total) return;

    char* ws = (char*)d_ws;
    ushort* xb   = (ushort*)(ws + o_xb);
    ushort* hring = xb;                       // ring overlays xb
    ushort* gx   = (ushort*)(ws + o_gx);
    ushort* wihb = (ushort*)(ws + o_wih);
    ushort* whhb = (ushort*)(ws + o_whh);
    float*  bias = (float*)(ws + o_bias);
    unsigned* flags = (unsigned*)(ws + o_flags);

    // conversions + bias + flag reset
    f2b_kernel<<<(int)(n_x / 1024), 256, 0, stream>>>(xb, x, (int)n_x);
    f2b_kernel<<<(int)(n_w / 1024), 256, 0, stream>>>(wihb, W_ih, (int)n_w);
    f2b_kernel<<<(int)(n_w / 1024), 256, 0, stream>>>(whhb, W_hh, (int)n_w);
    bias_kernel<<<GDIM / 256, 256, 0, stream>>>(bias, b_ih, b_hh);
    hipMemsetAsync(flags, 0, flags_bytes, stream);

    // gates_x = x @ W_ih^T  (M=32768, N=4096, K=1024)
    {
        dim3 grid(GDIM / 128, (S_LEN * BATCH) / 128);
        gemm_bt_kernel<<<grid, 256, 0, stream>>>(xb, wihb, gx, S_LEN * BATCH, GDIM, IDIM);
    }

    // h0 -> ring slot 0 (AFTER the GEMM: it overwrites the head of xb)
    f2b_kernel<<<(BATCH * HDIM) / 1024, 256, 0, stream>>>(hring, h0, BATCH * HDIM);

    // persistent recurrence (cooperative: all 64 blocks co-resident)
    {
        const ushort* gx_c = gx;
        const ushort* whh_c = whhb;
        const float* bias_c = bias;
        void* args[] = { (void*)&gx_c, (void*)&hring, (void*)&whh_c,
                         (void*)&bias_c, (void*)&c0, (void*)&out, (void*)&flags };
        hipLaunchCooperativeKernel((const void*)lstm_persistent, dim3(64), dim3(512),
                                   args, 0, stream);
    }
}

// Round 3
// 2327.680 us; speedup vs baseline: 4.0251x; 4.0251x over previous
//
#include <hip/hip_runtime.h>
#include <hip/hip_bf16.h>
#include <math.h>

// LSTM: S=512, B=64, I=1024, H=1024
// out[S,B,H] fp32, then h_last[B,H], c_last[B,H]
//
//  1) convert x,W_ih,W_hh -> bf16 in ws
//  2) gates_x[S*B,4H] = x @ W_ih^T  (128x128 MFMA GEMM, bf16 out)
//  3) ONE persistent cooperative kernel runs all 512 steps.
//     R6 decomposition: batches are INDEPENDENT chains, so run 4 separate
//     rings of 16 batches each. Each ring = 64 col-blocks (R0's proven
//     structure with M scaled 64->16). Grid = 256 blocks on 256 CUs.
//     Per ring-step: gather 32 KiB (vs 128), LDS traffic ~176 KiB (vs
//     ~655), 16-deep MFMA chain per wave (vs 64). Sync protocol identical
//     to R0 (sc1 publish -> vmcnt drain -> per-ring flags -> wave0 poll).

#define S_LEN 512
#define BATCH 64
#define IDIM 1024
#define HDIM 1024
#define GDIM 4096
#define MAGIC 0x1337BEEFu
#define HSLOT (BATCH * HDIM)   // 65536 ushorts = 128 KiB per ring slot
#define NRING 4
#define RB 16                  // batches per ring

typedef __bf16 bf16x8 __attribute__((ext_vector_type(8)));
typedef float f32x4 __attribute__((ext_vector_type(4)));

__device__ inline ushort f2b(float f) {
    union { float f; unsigned u; } v; v.f = f;
    unsigned u = v.u;
    unsigned r = (u + 0x7fffu + ((u >> 16) & 1u)) >> 16;
    return (ushort)r;
}
__device__ inline float b2f(ushort u) {
    union { unsigned u; float f; } v; v.u = ((unsigned)u) << 16;
    return v.f;
}
__device__ inline float sigmoidf_(float x) { return 1.f / (1.f + __expf(-x)); }
__device__ inline float tanhf_(float x) {
    return 1.f - 2.f / (__expf(2.f * x) + 1.f);
}

// ---------- conversion kernels ----------
__global__ __launch_bounds__(256) void f2b_kernel(ushort* __restrict__ dst,
                                                  const float* __restrict__ src, int n) {
    int i = (blockIdx.x * 256 + threadIdx.x) * 4;
    if (i < n) {
        float4 v = *(const float4*)(src + i);
        ushort4 o;
        o.x = f2b(v.x); o.y = f2b(v.y); o.z = f2b(v.z); o.w = f2b(v.w);
        *(ushort4*)(dst + i) = o;
    }
}

__global__ __launch_bounds__(256) void bias_kernel(float* __restrict__ bias,
                                                   const float* __restrict__ b_ih,
                                                   const float* __restrict__ b_hh) {
    int i = blockIdx.x * 256 + threadIdx.x;
    if (i < GDIM) bias[i] = b_ih[i] + b_hh[i];
}

// ---------- big GEMM: C[M,N] = A[M,K] @ B[N,K]^T ----------
#define LDSS 72
__global__ __launch_bounds__(256) void gemm_bt_kernel(const ushort* __restrict__ A,
                                                      const ushort* __restrict__ B,
                                                      ushort* __restrict__ C,
                                                      int M, int N, int K) {
    __shared__ __align__(16) ushort As[128 * LDSS];
    __shared__ __align__(16) ushort Bs[128 * LDSS];
    const int tid = threadIdx.x;
    const int lane = tid & 63;
    const int wave = tid >> 6;
    const int l15 = lane & 15;
    const int quad = lane >> 4;
    const int bn = blockIdx.x;
    const int bm = blockIdx.y;
    const int wrow = (wave & 1) * 64;
    const int wcol = (wave >> 1) * 64;

    f32x4 acc[4][4] = {};

    for (int kt = 0; kt < K; kt += 64) {
        #pragma unroll
        for (int i = 0; i < 4; i++) {
            int chunk = tid + i * 256;
            int r = chunk >> 3;
            int c8 = (chunk & 7) * 8;
            *(uint4*)&As[r * LDSS + c8] =
                *(const uint4*)&A[(size_t)(bm * 128 + r) * K + kt + c8];
            *(uint4*)&Bs[r * LDSS + c8] =
                *(const uint4*)&B[(size_t)(bn * 128 + r) * K + kt + c8];
        }
        __syncthreads();
        #pragma unroll
        for (int kc = 0; kc < 2; kc++) {
            const int ko = kc * 32 + quad * 8;
            bf16x8 af[4], bf[4];
            #pragma unroll
            for (int m = 0; m < 4; m++)
                af[m] = *(const bf16x8*)&As[(wrow + m * 16 + l15) * LDSS + ko];
            #pragma unroll
            for (int n = 0; n < 4; n++)
                bf[n] = *(const bf16x8*)&Bs[(wcol + n * 16 + l15) * LDSS + ko];
            #pragma unroll
            for (int m = 0; m < 4; m++)
                #pragma unroll
                for (int n = 0; n < 4; n++)
                    acc[m][n] = __builtin_amdgcn_mfma_f32_16x16x32_bf16(af[m], bf[n], acc[m][n], 0, 0, 0);
        }
        __syncthreads();
    }
    const int col0 = bn * 128 + wcol;
    const int row0 = bm * 128 + wrow;
    #pragma unroll
    for (int m = 0; m < 4; m++) {
        #pragma unroll
        for (int n = 0; n < 4; n++) {
            int col = col0 + n * 16 + l15;
            int rbase = row0 + m * 16 + quad * 4;
            #pragma unroll
            for (int r = 0; r < 4; r++)
                C[(size_t)(rbase + r) * N + col] = f2b(acc[m][n][r]);
        }
    }
}

// ---------- persistent recurrence kernel ----------
// Grid = 256 blocks = 4 rings x 64 col-blocks. Ring r owns batches
// [r*16, r*16+16) -- an independent LSTM chain (no cross-ring sync).
// Within a ring, col-block blk owns h-cols [blk*16, blk*16+16).
// 512 threads = 8 waves: wave wv -> gate = wv&3, khalf = wv>>2.
// Each wave: 16x16 output tile (16 batches x 16 gate-cols) over K=512,
// partials summed in LDS. W_hh b-frags in regs: 16 x bf16x8 = 64 VGPR.
#define HS2 1032        // Hs row stride in elems (R0-proven conflict floor)
#define GS_BS 17        // Gs per-batch stride (floats)
#define GS_GATE (16 * GS_BS)
#define GS_KH (4 * GS_GATE)

__global__ __launch_bounds__(512, 2) void lstm_persistent(
    const ushort* __restrict__ gx,
    ushort* __restrict__ hring,
    const ushort* __restrict__ Whh,
    const float* __restrict__ bias,
    const float* __restrict__ c0,
    float* __restrict__ out,
    unsigned* __restrict__ flags)
{
    __shared__ __align__(16) ushort Hs[RB * HS2];    // 33,024 B
    __shared__ float Gs[2 * GS_KH];                  //  8,704 B

    const int tid = threadIdx.x;
    const int lane = tid & 63;
    const int wv = tid >> 6;
    const int gate = wv & 3;
    const int kh = wv >> 2;
    const int l15 = lane & 15;
    const int quad = lane >> 4;
    const int bid = blockIdx.x;
    const int ring = bid >> 6;
    const int blk = bid & 63;

    // ---- preload W fragments (once): rows gate*1024+blk*16+l15, K-half kh ----
    bf16x8 wf[16];
    {
        const ushort* wrow = Whh + ((size_t)(gate * 1024 + blk * 16 + l15)) * 1024
                           + kh * 512 + quad * 8;
        #pragma unroll
        for (int ks = 0; ks < 16; ks++)
            wf[ks] = *(const bf16x8*)(wrow + ks * 32);
    }

    // ---- pointwise per-thread state: threads 0..127 own (pb, pj), (pb, pj+1) ----
    const bool pw = (tid < 128);
    const int pb = tid >> 3;            // local batch 0..15 (when pw)
    const int pj = (tid * 2) & 15;
    const int gb = ring * RB + pb;      // global batch
    const int pcol = blk * 16 + pj;
    float2 creg = {0.f, 0.f};
    if (pw) creg = *(const float2*)&c0[(size_t)gb * HDIM + pcol];
    float bsum[4][2];
    #pragma unroll
    for (int g = 0; g < 4; g++) {
        bsum[g][0] = bias[g * 1024 + pcol];
        bsum[g][1] = bias[g * 1024 + pcol + 1];
    }
    const size_t gx_tb = (size_t)gb * GDIM + blk * 16 + pj;

    #pragma unroll 1
    for (int s = 0; s < S_LEN; s++) {
        const ushort* hsrc = hring + (size_t)s * HSLOT + (size_t)ring * RB * HDIM;

        // prefetch gx[s] (independent of h) before the flag wait
        ushort2 gxr[4] = {};
        if (pw) {
            const ushort* gxs = gx + (size_t)s * BATCH * GDIM + gx_tb;
            #pragma unroll
            for (int g = 0; g < 4; g++)
                gxr[g] = *(const ushort2*)(gxs + g * 1024);
        }

        // wait for this ring's h_s: wave0 polls the ring's 64 flags.
        if (s > 0) {
            if (wv == 0) {
                const unsigned* fl = flags + ((size_t)s * NRING + ring) * 64;
                while (true) {
                    unsigned v = __hip_atomic_load(&fl[lane], __ATOMIC_RELAXED,
                                                   __HIP_MEMORY_SCOPE_AGENT);
                    if (__ballot(v != MAGIC) == 0ull) break;
                    __builtin_amdgcn_s_sleep(2);
                }
            }
            __syncthreads();
        }

        // gather ring's h slice (16x1024 bf16 = 32 KiB) via sc1 8B loads,
        // stage into LDS. 8 x 8B per thread.
        {
            const unsigned long long* h64 = (const unsigned long long*)hsrc;
            unsigned long long hr[8];
            #pragma unroll
            for (int c = 0; c < 8; c++)
                hr[c] = __hip_atomic_load(&h64[c * 512 + tid], __ATOMIC_RELAXED,
                                          __HIP_MEMORY_SCOPE_AGENT);
            #pragma unroll
            for (int c = 0; c < 8; c++) {
                int u = c * 512 + tid;
                int row = u >> 8;             // 256 x 8B per 1024-col row
                int col = (u & 255) * 4;      // elem offset
                *(unsigned long long*)&Hs[row * HS2 + col] = hr[c];
            }
        }
        __syncthreads();

        // MFMA: wave (gate, kh) computes 16 batches x 16 cols over K=512
        f32x4 acc = {0.f, 0.f, 0.f, 0.f};
        const int arow = l15 * HS2 + kh * 512 + quad * 8;
        #pragma unroll
        for (int ks = 0; ks < 16; ks++) {
            bf16x8 a = *(const bf16x8*)&Hs[arow + ks * 32];
            acc = __builtin_amdgcn_mfma_f32_16x16x32_bf16(a, wf[ks], acc, 0, 0, 0);
        }

        // exchange partial gates through LDS (C layout: col=l15, row=quad*4+r)
        #pragma unroll
        for (int r = 0; r < 4; r++)
            Gs[kh * GS_KH + gate * GS_GATE + (quad * 4 + r) * GS_BS + l15] = acc[r];
        __syncthreads();

        // pointwise: threads 0..127, 2 elements each (sum the 2 K-partials)
        float hv[2], cv[2];
        if (pw) {
            #pragma unroll
            for (int u = 0; u < 2; u++) {
                float cold = u ? creg.y : creg.x;
                int gsb = pb * GS_BS + pj + u;
                float g0 = Gs[0 * GS_GATE + gsb] + Gs[GS_KH + 0 * GS_GATE + gsb] + bsum[0][u] + b2f(u ? gxr[0].y : gxr[0].x);
                float g1 = Gs[1 * GS_GATE + gsb] + Gs[GS_KH + 1 * GS_GATE + gsb] + bsum[1][u] + b2f(u ? gxr[1].y : gxr[1].x);
                float g2 = Gs[2 * GS_GATE + gsb] + Gs[GS_KH + 2 * GS_GATE + gsb] + bsum[2][u] + b2f(u ? gxr[2].y : gxr[2].x);
                float g3 = Gs[3 * GS_GATE + gsb] + Gs[GS_KH + 3 * GS_GATE + gsb] + bsum[3][u] + b2f(u ? gxr[3].y : gxr[3].x);
                float ig = sigmoidf_(g0);
                float fg = sigmoidf_(g1);
                float gg = tanhf_(g2);
                float og = sigmoidf_(g3);
                float cn = fg * cold + ig * gg;
                float hn = og * tanhf_(cn);
                cv[u] = cn; hv[u] = hn;
            }
            creg.x = cv[0]; creg.y = cv[1];

            // publish h_{s+1} into the NEXT ring slot: sc1 write-through store
            if (s < S_LEN - 1) {
                ushort* hdst = hring + (size_t)(s + 1) * HSLOT;
                unsigned hword = (unsigned)f2b(hv[0]) | ((unsigned)f2b(hv[1]) << 16);
                __hip_atomic_store((unsigned*)&hdst[(size_t)gb * HDIM + pcol], hword,
                                   __ATOMIC_RELAXED, __HIP_MEMORY_SCOPE_AGENT);
            }
        }

        // __syncthreads drains each wave's vmcnt: all sc1 h stores acked at
        // the coherence point (LLC) before the flag store issues.
        __syncthreads();
        if (tid == 0 && s < S_LEN - 1) {
            asm volatile("s_waitcnt vmcnt(0)" ::: "memory");
            __hip_atomic_store(&flags[((size_t)(s + 1) * NRING + ring) * 64 + blk],
                               MAGIC, __ATOMIC_RELAXED, __HIP_MEMORY_SCOPE_AGENT);
        }

        // out store AFTER the flag publish: HBM write ack overlaps the next
        // step's poll instead of sitting on the handoff path.
        if (pw) {
            float2 ho; ho.x = hv[0]; ho.y = hv[1];
            *(float2*)&out[(size_t)s * BATCH * HDIM + (size_t)gb * HDIM + pcol] = ho;
            if (s == S_LEN - 1) {
                float* tail = out + (size_t)S_LEN * BATCH * HDIM;
                *(float2*)&tail[(size_t)gb * HDIM + pcol] = ho;
                float2 co; co.x = cv[0]; co.y = cv[1];
                *(float2*)&tail[BATCH * HDIM + (size_t)gb * HDIM + pcol] = co;
            }
        }
    }
}

extern "C" void kernel_launch(void* const* d_in, const int* in_sizes, int n_in,
                              void* d_out, int out_size, void* d_ws, size_t ws_size,
                              hipStream_t stream) {
    const float* x    = (const float*)d_in[0];
    const float* h0   = (const float*)d_in[1];
    const float* c0   = (const float*)d_in[2];
    const float* W_ih = (const float*)d_in[3];
    const float* b_ih = (const float*)d_in[4];
    const float* W_hh = (const float*)d_in[5];
    const float* b_hh = (const float*)d_in[6];
    float* out = (float*)d_out;

    const size_t n_x  = (size_t)S_LEN * BATCH * IDIM;
    const size_t n_w  = (size_t)GDIM * IDIM;
    // xb (64 MiB) doubles as the h ring: 512 slots x 128 KiB, reused only
    // after the GEMM has consumed x.
    const size_t o_xb    = 0;
    const size_t o_gx    = o_xb + n_x * 2;
    const size_t o_wih   = o_gx + (size_t)S_LEN * BATCH * GDIM * 2;
    const size_t o_whh   = o_wih + n_w * 2;
    const size_t o_bias  = o_whh + n_w * 2;
    const size_t o_flags = o_bias + GDIM * 4;
    const size_t flags_bytes = (size_t)(S_LEN + 1) * NRING * 64 * 4;
    const size_t total  = o_flags + flags_bytes;
    if (ws_size < total) return;

    char* ws = (char*)d_ws;
    ushort* xb   = (ushort*)(ws + o_xb);
    ushort* hring = xb;                       // ring overlays xb
    ushort* gx   = (ushort*)(ws + o_gx);
    ushort* wihb = (ushort*)(ws + o_wih);
    ushort* whhb = (ushort*)(ws + o_whh);
    float*  bias = (float*)(ws + o_bias);
    unsigned* flags = (unsigned*)(ws + o_flags);

    // conversions + bias + flag reset
    f2b_kernel<<<(int)(n_x / 1024), 256, 0, stream>>>(xb, x, (int)n_x);
    f2b_kernel<<<(int)(n_w / 1024), 256, 0, stream>>>(wihb, W_ih, (int)n_w);
    f2b_kernel<<<(int)(n_w / 1024), 256, 0, stream>>>(whhb, W_hh, (int)n_w);
    bias_kernel<<<GDIM / 256, 256, 0, stream>>>(bias, b_ih, b_hh);
    hipMemsetAsync(flags, 0, flags_bytes, stream);

    // gates_x = x @ W_ih^T  (M=32768, N=4096, K=1024)
    {
        dim3 grid(GDIM / 128, (S_LEN * BATCH) / 128);
        gemm_bt_kernel<<<grid, 256, 0, stream>>>(xb, wihb, gx, S_LEN * BATCH, IDIM == 0 ? 0 : GDIM, IDIM);
    }

    // h0 -> ring slot 0 (AFTER the GEMM: it overwrites the head of xb)
    f2b_kernel<<<(BATCH * HDIM) / 1024, 256, 0, stream>>>(hring, h0, BATCH * HDIM);

    // persistent recurrence (cooperative: all 256 blocks co-resident)
    {
        const ushort* gx_c = gx;
        const ushort* whh_c = whhb;
        const float* bias_c = bias;
        void* args[] = { (void*)&gx_c, (void*)&hring, (void*)&whh_c,
                         (void*)&bias_c, (void*)&c0, (void*)&out, (void*)&flags };
        hipLaunchCooperativeKernel((const void*)lstm_persistent, dim3(NRING * 64), dim3(512),
                                   args, 0, stream);
    }
}